// Round 4
// baseline (391.146 us; speedup 1.0000x reference)
//
#include <hip/hip_runtime.h>
#include <hip/hip_fp16.h>
#include <math.h>

typedef __attribute__((ext_vector_type(8))) short short8;
typedef __attribute__((ext_vector_type(8))) unsigned short ushort8_t;
typedef __attribute__((ext_vector_type(4))) float floatx4;

__device__ __forceinline__ float bf2f(unsigned short u){
  return __uint_as_float(((unsigned int)u) << 16);
}
__device__ __forceinline__ unsigned short f2bf(float f){
  unsigned int x = __float_as_uint(f);
  unsigned int r = x + 0x7fff + ((x >> 16) & 1);   // RNE
  return (unsigned short)(r >> 16);
}
__device__ __forceinline__ unsigned pack_h2(float a, float b){
  return ((unsigned)__half_as_ushort(__float2half_rn(b)) << 16) |
         (unsigned)__half_as_ushort(__float2half_rn(a));
}
__device__ __forceinline__ float unpack_h(unsigned u, int hi){
  unsigned short us = hi ? (unsigned short)(u >> 16) : (unsigned short)(u & 0xffff);
  return __half2float(__ushort_as_half(us));
}

__device__ __forceinline__ float wsumf(float v){
#pragma unroll
  for (int o = 32; o; o >>= 1) v += __shfl_xor(v, o, 64);
  return v;
}
__device__ __forceinline__ float wsumf16(float v){
#pragma unroll
  for (int o = 8; o; o >>= 1) v += __shfl_xor(v, o, 64);
  return v;
}

// ---------------------------------------------------------------- degree/count
__global__ __launch_bounds__(256) void k_count(const int* __restrict__ dst,
    const float* __restrict__ eattr, int* __restrict__ deg,
    float* __restrict__ sattr, int E){
  int e = blockIdx.x * 256 + threadIdx.x;
  if (e >= E) return;
  int d = dst[e];
  atomicAdd(&deg[d], 1);
  atomicAdd(&sattr[d], eattr[e]);
}

// ---------------------------------------------------------------- scan (3 phases)
__global__ __launch_bounds__(256) void k_scan1(const int* __restrict__ deg,
    int* __restrict__ row_ptr, int* __restrict__ bsum, int n){
  __shared__ int sm[2][256];
  int tid = threadIdx.x, gid = blockIdx.x * 256 + tid;
  int v = (gid < n) ? deg[gid] : 0;
  sm[0][tid] = v; __syncthreads();
  int pin = 0;
  for (int off = 1; off < 256; off <<= 1){
    int t = sm[pin][tid];
    if (tid >= off) t += sm[pin][tid - off];
    sm[pin ^ 1][tid] = t; pin ^= 1; __syncthreads();
  }
  int incl = sm[pin][tid];
  if (gid < n) row_ptr[gid] = incl - v;
  if (tid == 255) bsum[blockIdx.x] = incl;
}

__global__ __launch_bounds__(256) void k_scan2(const int* __restrict__ bsum,
    int* __restrict__ bofs, int nb){
  __shared__ int sm[2][256];
  int tid = threadIdx.x;
  int v = (tid < nb) ? bsum[tid] : 0;
  sm[0][tid] = v; __syncthreads();
  int pin = 0;
  for (int off = 1; off < 256; off <<= 1){
    int t = sm[pin][tid];
    if (tid >= off) t += sm[pin][tid - off];
    sm[pin ^ 1][tid] = t; pin ^= 1; __syncthreads();
  }
  bofs[tid] = sm[pin][tid] - v;
}

__global__ __launch_bounds__(256) void k_scan3(int* __restrict__ row_ptr,
    const int* __restrict__ bofs, const int* __restrict__ deg,
    const float* __restrict__ sattr, float* __restrict__ lattr, int n, int E){
  int gid = blockIdx.x * 256 + threadIdx.x;
  if (gid >= n) return;
  row_ptr[gid] += bofs[gid >> 8];
  float d = (float)deg[gid];
  lattr[gid] = sattr[gid] / fmaxf(d, 1.0f);
  if (gid == 0) row_ptr[n] = E;
}

// ---------------------------------------------------------------- CSR scatter {src, dst, eattr, 0}
__global__ __launch_bounds__(256) void k_scatter(const int* __restrict__ src,
    const int* __restrict__ dst, const float* __restrict__ eattr,
    const int* __restrict__ row_ptr, int* __restrict__ cursor,
    int4* __restrict__ csr4, int E){
  int e = blockIdx.x * 256 + threadIdx.x;
  if (e >= E) return;
  int d = dst[e];
  int pos = row_ptr[d] + atomicAdd(&cursor[d], 1);
  csr4[pos] = make_int4(src[e], d, __float_as_int(eattr[e]), 0);
}

// ---------------------------------------------------------------- pack B into MFMA frag layout
__global__ void k_packB(const float* __restrict__ W, unsigned short* __restrict__ Bp,
                        int K, int N){
  int lane = threadIdx.x;
  int nt = blockIdx.x, kc = blockIdx.y, nkc = gridDim.y;
  int col = nt * 16 + (lane & 15);
  int krow = kc * 32 + (lane >> 4) * 8;
  unsigned short tmp[8];
#pragma unroll
  for (int j = 0; j < 8; j++) tmp[j] = f2bf(W[(size_t)(krow + j) * N + col]);
  unsigned short* dstp = Bp + (((size_t)nt * nkc + kc) * 64 + lane) * 8;
  *(ushort4*)(dstp)     = make_ushort4(tmp[0], tmp[1], tmp[2], tmp[3]);
  *(ushort4*)(dstp + 4) = make_ushort4(tmp[4], tmp[5], tmp[6], tmp[7]);
}

// ---------------------------------------------------------------- bf16 MFMA GEMM (bf16 A)
template<int N, int K>
__global__ __launch_bounds__(256) void k_gemm_mfma(const unsigned short* __restrict__ A,
    const unsigned short* __restrict__ Bp, unsigned short* __restrict__ C, int M){
  constexpr int NKC = K / 32, NNT = N / 16;
  __shared__ unsigned short Bs[N * K];
  {
    const uint4* srcp = (const uint4*)Bp;
    uint4* dstp = (uint4*)Bs;
    const int total = (N * K * 2) / 16;
    for (int i = threadIdx.x; i < total; i += 256) dstp[i] = srcp[i];
  }
  __syncthreads();
  int wave = threadIdx.x >> 6, lane = threadIdx.x & 63;
  int quad = lane >> 4, col = lane & 15;
  int r0 = (blockIdx.x * 4 + wave) * 16;
  int rowc = min(r0 + col, M - 1);
  short8 af[NKC];
#pragma unroll
  for (int kc = 0; kc < NKC; kc++)
    af[kc] = *(const short8*)(A + (size_t)rowc * K + kc * 32 + quad * 8);
  floatx4 acc[NNT];
#pragma unroll
  for (int nt = 0; nt < NNT; nt++) acc[nt] = (floatx4){0.f, 0.f, 0.f, 0.f};
#pragma unroll
  for (int kc = 0; kc < NKC; kc++){
#pragma unroll
    for (int nt = 0; nt < NNT; nt++){
      short8 bfv = *(const short8*)(&Bs[((nt * NKC + kc) * 64 + lane) * 8]);
      acc[nt] = __builtin_amdgcn_mfma_f32_16x16x32_bf16(af[kc], bfv, acc[nt], 0, 0, 0);
    }
  }
#pragma unroll
  for (int nt = 0; nt < NNT; nt++){
#pragma unroll
    for (int i = 0; i < 4; i++){
      int r = r0 + quad * 4 + i;
      if (r < M) C[(size_t)r * N + nt * 16 + col] = f2bf(acc[nt][i]);
    }
  }
}

// ---------------------------------------------------------------- bf16 MFMA GEMM, fp32 A (fused cast)
template<int N, int K>
__global__ __launch_bounds__(256) void k_gemm_mfma_f32(const float* __restrict__ A,
    const unsigned short* __restrict__ Bp, unsigned short* __restrict__ C, int M){
  constexpr int NKC = K / 32, NNT = N / 16;
  __shared__ unsigned short Bs[N * K];
  {
    const uint4* srcp = (const uint4*)Bp;
    uint4* dstp = (uint4*)Bs;
    const int total = (N * K * 2) / 16;
    for (int i = threadIdx.x; i < total; i += 256) dstp[i] = srcp[i];
  }
  __syncthreads();
  int wave = threadIdx.x >> 6, lane = threadIdx.x & 63;
  int quad = lane >> 4, col = lane & 15;
  int r0 = (blockIdx.x * 4 + wave) * 16;
  int rowc = min(r0 + col, M - 1);
  short8 af[NKC];
#pragma unroll
  for (int kc = 0; kc < NKC; kc++){
    float4 a0 = *(const float4*)(A + (size_t)rowc * K + kc * 32 + quad * 8);
    float4 a1 = *(const float4*)(A + (size_t)rowc * K + kc * 32 + quad * 8 + 4);
    short8 t;
    t[0] = (short)f2bf(a0.x); t[1] = (short)f2bf(a0.y);
    t[2] = (short)f2bf(a0.z); t[3] = (short)f2bf(a0.w);
    t[4] = (short)f2bf(a1.x); t[5] = (short)f2bf(a1.y);
    t[6] = (short)f2bf(a1.z); t[7] = (short)f2bf(a1.w);
    af[kc] = t;
  }
  floatx4 acc[NNT];
#pragma unroll
  for (int nt = 0; nt < NNT; nt++) acc[nt] = (floatx4){0.f, 0.f, 0.f, 0.f};
#pragma unroll
  for (int kc = 0; kc < NKC; kc++){
#pragma unroll
    for (int nt = 0; nt < NNT; nt++){
      short8 bfv = *(const short8*)(&Bs[((nt * NKC + kc) * 64 + lane) * 8]);
      acc[nt] = __builtin_amdgcn_mfma_f32_16x16x32_bf16(af[kc], bfv, acc[nt], 0, 0, 0);
    }
  }
#pragma unroll
  for (int nt = 0; nt < NNT; nt++){
#pragma unroll
    for (int i = 0; i < 4; i++){
      int r = r0 + quad * 4 + i;
      if (r < M) C[(size_t)r * N + nt * 16 + col] = f2bf(acc[nt][i]);
    }
  }
}

// ---------------------------------------------------------------- edge coeffs
__global__ void k_ce(const float* __restrict__ We1, const float* __restrict__ ae1,
    const float* __restrict__ We2, const float* __restrict__ ae2,
    float* __restrict__ ce){
  int lane = threadIdx.x;
  float p0 = We1[lane]       * ae1[lane];
  float p1 = We1[64 + lane]  * ae1[64 + lane];
  float p2 = We1[128 + lane] * ae1[128 + lane];
  float p3 = We1[192 + lane] * ae1[192 + lane];
  float p4 = We2[lane]       * ae2[lane];
  p0 = wsumf(p0); p1 = wsumf(p1); p2 = wsumf(p2); p3 = wsumf(p3); p4 = wsumf(p4);
  if (lane == 0){ ce[0] = p0; ce[1] = p1; ce[2] = p2; ce[3] = p3; ce[4] = p4; }
}

// ---------------------------------------------------------------- att scores L1 (bf16 h)
__global__ __launch_bounds__(256) void k_attscore1(const unsigned short* __restrict__ h,
    const float* __restrict__ as_, const float* __restrict__ ad_,
    float* __restrict__ a_src, float* __restrict__ a_dst, int n){
  int node = blockIdx.x * 4 + (threadIdx.x >> 6);
  if (node >= n) return;
  int lane = threadIdx.x & 63;
  ushort4 hv = *(const ushort4*)(h + (size_t)node * 256 + lane * 4);
  float4 av = *(const float4*)(as_ + lane * 4);
  float4 dv = *(const float4*)(ad_ + lane * 4);
  float h0 = bf2f(hv.x), h1 = bf2f(hv.y), h2 = bf2f(hv.z), h3 = bf2f(hv.w);
  float s = h0 * av.x + h1 * av.y + h2 * av.z + h3 * av.w;
  float d = h0 * dv.x + h1 * dv.y + h2 * dv.z + h3 * dv.w;
  s = wsumf16(s); d = wsumf16(d);
  if ((lane & 15) == 0){
    a_src[node * 4 + (lane >> 4)] = s;
    a_dst[node * 4 + (lane >> 4)] = d;
  }
}

// ---------------------------------------------------------------- edge weight prepass L1
// wcsr[slot] = {src, half2(w0,w1), half2(w2,w3), 0}
__global__ __launch_bounds__(256) void k_wpre1(const int4* __restrict__ csr4,
    const float* __restrict__ a_src, const float* __restrict__ a_dst,
    const float* __restrict__ ce, int4* __restrict__ wcsr, int E){
  int e = blockIdx.x * 256 + threadIdx.x;
  if (e >= E) return;
  int4 c = csr4[e];
  float ea = __int_as_float(c.z);
  float4 as4 = *(const float4*)(a_src + (size_t)c.x * 4);
  float4 ad4 = *(const float4*)(a_dst + (size_t)c.y * 4);
  float4 ce4 = *(const float4*)ce;
  float a0 = as4.x + ad4.x + ea * ce4.x; a0 = a0 > 0.f ? a0 : 0.2f * a0;
  float a1 = as4.y + ad4.y + ea * ce4.y; a1 = a1 > 0.f ? a1 : 0.2f * a1;
  float a2 = as4.z + ad4.z + ea * ce4.z; a2 = a2 > 0.f ? a2 : 0.2f * a2;
  float a3 = as4.w + ad4.w + ea * ce4.w; a3 = a3 > 0.f ? a3 : 0.2f * a3;
  unsigned u01 = pack_h2(__expf(a0), __expf(a1));
  unsigned u23 = pack_h2(__expf(a2), __expf(a3));
  wcsr[e] = make_int4(c.x, (int)u01, (int)u23, 0);
}

// ---------------------------------------------------------------- GAT layer 1
// Quarter-wave (16 lanes) per edge, 4 edges/iter; lane covers 16 channels (32 B).
__global__ __launch_bounds__(256) void k_gat1(
    const int* __restrict__ row_ptr, const int4* __restrict__ wcsr,
    const float* __restrict__ lattr,
    const float* __restrict__ a_src, const float* __restrict__ a_dst,
    const float* __restrict__ ce, const unsigned short* __restrict__ hpre,
    const float* __restrict__ bias, unsigned short* __restrict__ hout, int n){
  int node = blockIdx.x * 4 + (threadIdx.x >> 6);
  if (node >= n) return;
  int lane = threadIdx.x & 63;
  int q = lane >> 4, lsub = lane & 15, hq = lsub >> 2;
  int start = row_ptr[node], deg = row_ptr[node + 1] - start;
  int total = deg + 1;
  // self-loop weight (per head of this lane)
  float4 as4 = *(const float4*)(a_src + (size_t)node * 4);
  float4 ad4 = *(const float4*)(a_dst + (size_t)node * 4);
  float4 ce4 = *(const float4*)ce;
  float la = lattr[node];
  float asvh = hq == 0 ? as4.x : hq == 1 ? as4.y : hq == 2 ? as4.z : as4.w;
  float advh = hq == 0 ? ad4.x : hq == 1 ? ad4.y : hq == 2 ? ad4.z : ad4.w;
  float ceh  = hq == 0 ? ce4.x : hq == 1 ? ce4.y : hq == 2 ? ce4.z : ce4.w;
  float aself = asvh + advh + la * ceh;
  aself = aself > 0.f ? aself : 0.2f * aself;
  float wself = __expf(aself);
  float acc[16];
#pragma unroll
  for (int k = 0; k < 16; k++) acc[k] = 0.f;
  float dn = 0.f;
  for (int e = q; e < total; e += 4){
    int s; float wv;
    if (e < deg){
      int4 we = wcsr[start + e];
      s = we.x;
      unsigned wb = (hq & 2) ? (unsigned)we.z : (unsigned)we.y;
      wv = unpack_h(wb, hq & 1);
    } else { s = node; wv = wself; }
    dn += wv;
    const unsigned short* hp = hpre + (size_t)s * 256 + lsub * 16;
    ushort8_t hv0 = *(const ushort8_t*)(hp);
    ushort8_t hv1 = *(const ushort8_t*)(hp + 8);
#pragma unroll
    for (int k = 0; k < 8; k++) acc[k]     += wv * bf2f(hv0[k]);
#pragma unroll
    for (int k = 0; k < 8; k++) acc[k + 8] += wv * bf2f(hv1[k]);
  }
  dn += __shfl_xor(dn, 16, 64);
  dn += __shfl_xor(dn, 32, 64);
#pragma unroll
  for (int k = 0; k < 16; k++){
    acc[k] += __shfl_xor(acc[k], 16, 64);
    acc[k] += __shfl_xor(acc[k], 32, 64);
  }
  if (q == 0){
    float inv = 1.f / dn;
    float bb[16];
#pragma unroll
    for (int j = 0; j < 4; j++){
      float4 b4 = *(const float4*)(bias + lsub * 16 + j * 4);
      bb[j * 4 + 0] = b4.x; bb[j * 4 + 1] = b4.y;
      bb[j * 4 + 2] = b4.z; bb[j * 4 + 3] = b4.w;
    }
    ushort8_t o0, o1;
#pragma unroll
    for (int k = 0; k < 8; k++){
      float v = acc[k] * inv + bb[k];
      v = v > 0.f ? v : (__expf(v) - 1.f);
      o0[k] = f2bf(v);
    }
#pragma unroll
    for (int k = 0; k < 8; k++){
      float v = acc[k + 8] * inv + bb[k + 8];
      v = v > 0.f ? v : (__expf(v) - 1.f);
      o1[k] = f2bf(v);
    }
    unsigned short* op = hout + (size_t)node * 256 + lsub * 16;
    *(ushort8_t*)(op)     = o0;
    *(ushort8_t*)(op + 8) = o1;
  }
}

// ---------------------------------------------------------------- att scores L2 (bf16 h)
__global__ __launch_bounds__(256) void k_attscore2(const unsigned short* __restrict__ h,
    const float* __restrict__ as_, const float* __restrict__ ad_,
    float* __restrict__ a_src, float* __restrict__ a_dst, int n){
  int node = blockIdx.x * 4 + (threadIdx.x >> 6);
  if (node >= n) return;
  int lane = threadIdx.x & 63;
  float v = bf2f(h[(size_t)node * 64 + lane]);
  float s = wsumf(v * as_[lane]);
  float d = wsumf(v * ad_[lane]);
  if (lane == 0){ a_src[node] = s; a_dst[node] = d; }
}

// ---------------------------------------------------------------- edge weight prepass L2
__global__ __launch_bounds__(256) void k_wpre2(const int4* __restrict__ csr4,
    const float* __restrict__ a_src, const float* __restrict__ a_dst,
    const float* __restrict__ ce, int2* __restrict__ wcsr2, int E){
  int e = blockIdx.x * 256 + threadIdx.x;
  if (e >= E) return;
  int4 c = csr4[e];
  float ea = __int_as_float(c.z);
  float a = a_src[c.x] + a_dst[c.y] + ea * ce[4];
  a = a > 0.f ? a : 0.2f * a;
  wcsr2[e] = make_int2(c.x, __float_as_int(__expf(a)));
}

// ---------------------------------------------------------------- GAT layer 2 + pair projection
// 8-lane group per edge: 8 lanes x ushort8 = 64 channels, 8 edges/iter.
__global__ __launch_bounds__(256) void k_gat2(
    const int* __restrict__ row_ptr, const int2* __restrict__ wcsr2,
    const float* __restrict__ lattr,
    const float* __restrict__ a_src, const float* __restrict__ a_dst,
    const float* __restrict__ ce, const unsigned short* __restrict__ hpre,
    const float* __restrict__ bias, const float* __restrict__ Wlin,
    float* __restrict__ s1v, float* __restrict__ s2v, int n){
  int node = blockIdx.x * 4 + (threadIdx.x >> 6);
  if (node >= n) return;
  int lane = threadIdx.x & 63;
  int slot = lane >> 3, lsub = lane & 7;
  int start = row_ptr[node], deg = row_ptr[node + 1] - start;
  int total = deg + 1;
  float aself = a_src[node] + a_dst[node] + lattr[node] * ce[4];
  aself = aself > 0.f ? aself : 0.2f * aself;
  float wself = __expf(aself);
  float acc[8] = {0.f,0.f,0.f,0.f,0.f,0.f,0.f,0.f};
  float dn = 0.f;
  for (int e = slot; e < total; e += 8){
    int s; float wv;
    if (e < deg){ int2 se = wcsr2[start + e]; s = se.x; wv = __int_as_float(se.y); }
    else        { s = node; wv = wself; }
    dn += wv;
    ushort8_t hv = *(const ushort8_t*)(hpre + (size_t)s * 64 + lsub * 8);
#pragma unroll
    for (int k = 0; k < 8; k++) acc[k] += wv * bf2f(hv[k]);
  }
#pragma unroll
  for (int o = 8; o < 64; o <<= 1){
    dn += __shfl_xor(dn, o, 64);
#pragma unroll
    for (int k = 0; k < 8; k++) acc[k] += __shfl_xor(acc[k], o, 64);
  }
  float inv = 1.f / dn;
  float t1 = 0.f, t2 = 0.f;
#pragma unroll
  for (int k = 0; k < 8; k++){
    float v = acc[k] * inv + bias[lsub * 8 + k];
    t1 += v * Wlin[lsub * 8 + k];
    t2 += v * Wlin[64 + lsub * 8 + k];
  }
#pragma unroll
  for (int o = 1; o < 8; o <<= 1){
    t1 += __shfl_xor(t1, o, 64);
    t2 += __shfl_xor(t2, o, 64);
  }
  if (lane == 0){ s1v[node] = t1; s2v[node] = t2; }
}

// ---------------------------------------------------------------- pair head
__global__ __launch_bounds__(256) void k_pairs(const int* __restrict__ pairs,
    const float* __restrict__ s1v, const float* __restrict__ s2v,
    const float* __restrict__ blin, float* __restrict__ out, int P){
  int p = blockIdx.x * 256 + threadIdx.x;
  if (p >= P) return;
  int i = pairs[2 * p], j = pairs[2 * p + 1];
  float x = s1v[i] + s2v[j] + blin[0];
  out[p] = 1.f / (1.f + __expf(-x));
}

// ---------------------------------------------------------------- launch
extern "C" void kernel_launch(void* const* d_in, const int* in_sizes, int n_in,
                              void* d_out, int out_size, void* d_ws, size_t ws_size,
                              hipStream_t stream) {
  const float* x     = (const float*)d_in[0];
  const int*   esrc  = (const int*)  d_in[1];
  const int*   edst  = (const int*)  d_in[2];
  const float* eattr = (const float*)d_in[3];
  const int*   pairs = (const int*)  d_in[4];
  const float* W1    = (const float*)d_in[5];
  const float* We1   = (const float*)d_in[6];
  const float* as1   = (const float*)d_in[7];
  const float* ad1   = (const float*)d_in[8];
  const float* ae1   = (const float*)d_in[9];
  const float* b1    = (const float*)d_in[10];
  const float* W2    = (const float*)d_in[11];
  const float* We2   = (const float*)d_in[12];
  const float* as2   = (const float*)d_in[13];
  const float* ad2   = (const float*)d_in[14];
  const float* ae2   = (const float*)d_in[15];
  const float* b2    = (const float*)d_in[16];
  const float* Wlin  = (const float*)d_in[17];
  const float* blin  = (const float*)d_in[18];
  float* out = (float*)d_out;

  const int N = in_sizes[0] / 128;
  const int E = in_sizes[1];
  const int P = in_sizes[4] / 2;

  char* w = (char*)d_ws;
  size_t off = 0;
  auto alloc = [&](size_t bytes) -> size_t {
    size_t r = off; off = (off + bytes + 255) & ~(size_t)255; return r;
  };
  size_t o_deg    = alloc((size_t)N * 4);
  size_t o_sattr  = alloc((size_t)N * 4);
  size_t o_cursor = alloc((size_t)N * 4);
  size_t zero_end = off;
  size_t o_rowptr = alloc((size_t)(N + 1) * 4);
  size_t o_bsum   = alloc(1024);
  size_t o_bofs   = alloc(1024);
  size_t o_lattr  = alloc((size_t)N * 4);
  size_t o_csr4   = alloc((size_t)E * 16);
  size_t o_wcsr1  = alloc((size_t)E * 16);
  size_t o_wcsr2  = alloc((size_t)E * 8);
  size_t o_asrc1  = alloc((size_t)N * 16);
  size_t o_adst1  = alloc((size_t)N * 16);
  size_t o_asrc2  = alloc((size_t)N * 4);
  size_t o_adst2  = alloc((size_t)N * 4);
  size_t o_ce     = alloc(32);
  size_t o_s1     = alloc((size_t)N * 4);
  size_t o_s2     = alloc((size_t)N * 4);
  size_t o_W1p    = alloc(128 * 256 * 2);
  size_t o_W2p    = alloc(256 * 64 * 2);
  size_t o_h1preb = alloc((size_t)N * 256 * 2);
  size_t o_h1b    = alloc((size_t)N * 256 * 2);
  size_t o_h2preb = alloc((size_t)N * 64 * 2);
  (void)ws_size;

  int*   deg    = (int*)  (w + o_deg);
  float* sattr  = (float*)(w + o_sattr);
  int*   cursor = (int*)  (w + o_cursor);
  int*   rowptr = (int*)  (w + o_rowptr);
  int*   bsum   = (int*)  (w + o_bsum);
  int*   bofs   = (int*)  (w + o_bofs);
  float* lattr  = (float*)(w + o_lattr);
  int4*  csr4   = (int4*) (w + o_csr4);
  int4*  wcsr1  = (int4*) (w + o_wcsr1);
  int2*  wcsr2  = (int2*) (w + o_wcsr2);
  float* asrc1  = (float*)(w + o_asrc1);
  float* adst1  = (float*)(w + o_adst1);
  float* asrc2  = (float*)(w + o_asrc2);
  float* adst2  = (float*)(w + o_adst2);
  float* ce     = (float*)(w + o_ce);
  float* s1v    = (float*)(w + o_s1);
  float* s2v    = (float*)(w + o_s2);
  unsigned short* W1p    = (unsigned short*)(w + o_W1p);
  unsigned short* W2p    = (unsigned short*)(w + o_W2p);
  unsigned short* h1preb = (unsigned short*)(w + o_h1preb);
  unsigned short* h1b    = (unsigned short*)(w + o_h1b);
  unsigned short* h2preb = (unsigned short*)(w + o_h2preb);

  hipMemsetAsync(w, 0, zero_end, stream);

  int ebl = (E + 255) / 256;
  int nbl = (N + 255) / 256;
  int wbl = (N + 3) / 4;

  // CSR build
  k_count<<<ebl, 256, 0, stream>>>(edst, eattr, deg, sattr, E);
  k_scan1<<<nbl, 256, 0, stream>>>(deg, rowptr, bsum, N);
  k_scan2<<<1, 256, 0, stream>>>(bsum, bofs, nbl);
  k_scan3<<<nbl, 256, 0, stream>>>(rowptr, bofs, deg, sattr, lattr, N, E);
  k_scatter<<<ebl, 256, 0, stream>>>(esrc, edst, eattr, rowptr, cursor, csr4, E);

  // weight packing + edge coeffs
  k_packB<<<dim3(16, 4), 64, 0, stream>>>(W1, W1p, 128, 256);
  k_packB<<<dim3(4, 8), 64, 0, stream>>>(W2, W2p, 256, 64);
  k_ce<<<1, 64, 0, stream>>>(We1, ae1, We2, ae2, ce);

  // layer 1
  k_gemm_mfma_f32<256, 128><<<(N + 63) / 64, 256, 0, stream>>>(x, W1p, h1preb, N);
  k_attscore1<<<wbl, 256, 0, stream>>>(h1preb, as1, ad1, asrc1, adst1, N);
  k_wpre1<<<ebl, 256, 0, stream>>>(csr4, asrc1, adst1, ce, wcsr1, E);
  k_gat1<<<wbl, 256, 0, stream>>>(rowptr, wcsr1, lattr, asrc1, adst1, ce,
                                  h1preb, b1, h1b, N);
  // layer 2
  k_gemm_mfma<64, 256><<<(N + 63) / 64, 256, 0, stream>>>(h1b, W2p, h2preb, N);
  k_attscore2<<<wbl, 256, 0, stream>>>(h2preb, as2, ad2, asrc2, adst2, N);
  k_wpre2<<<ebl, 256, 0, stream>>>(csr4, asrc2, adst2, ce, wcsr2, E);
  k_gat2<<<wbl, 256, 0, stream>>>(rowptr, wcsr2, lattr, asrc2, adst2, ce,
                                  h2preb, b2, Wlin, s1v, s2v, N);
  // pair head
  k_pairs<<<(P + 255) / 256, 256, 0, stream>>>(pairs, s1v, s2v, blin, out, P);
}

// Round 5
// 322.509 us; speedup vs baseline: 1.2128x; 1.2128x over previous
//
#include <hip/hip_runtime.h>
#include <hip/hip_fp16.h>
#include <math.h>

typedef __attribute__((ext_vector_type(8))) short short8;
typedef __attribute__((ext_vector_type(8))) unsigned short ushort8_t;
typedef __attribute__((ext_vector_type(4))) float floatx4;

__device__ __forceinline__ float bf2f(unsigned short u){
  return __uint_as_float(((unsigned int)u) << 16);
}
__device__ __forceinline__ unsigned short f2bf(float f){
  unsigned int x = __float_as_uint(f);
  unsigned int r = x + 0x7fff + ((x >> 16) & 1);   // RNE
  return (unsigned short)(r >> 16);
}
__device__ __forceinline__ unsigned pack_h2(float a, float b){
  return ((unsigned)__half_as_ushort(__float2half_rn(b)) << 16) |
         (unsigned)__half_as_ushort(__float2half_rn(a));
}
__device__ __forceinline__ float unpack_h(unsigned u, int hi){
  unsigned short us = hi ? (unsigned short)(u >> 16) : (unsigned short)(u & 0xffff);
  return __half2float(__ushort_as_half(us));
}

__device__ __forceinline__ float wsumf(float v){
#pragma unroll
  for (int o = 32; o; o >>= 1) v += __shfl_xor(v, o, 64);
  return v;
}
__device__ __forceinline__ float wsumf16(float v){
#pragma unroll
  for (int o = 8; o; o >>= 1) v += __shfl_xor(v, o, 64);
  return v;
}

// ---------------------------------------------------------------- count: ONE u64 atomic per edge
// degp[d] bits[63:40] = degree count, bits[39:0] = sum(eattr) in 2^-24 fixed point.
// rank[e] = this edge's slot index within its dst row (from atomic return).
__global__ __launch_bounds__(256) void k_count(const int* __restrict__ dst,
    const float* __restrict__ eattr, unsigned long long* __restrict__ degp,
    int* __restrict__ rank, int E){
  int e = blockIdx.x * 256 + threadIdx.x;
  if (e >= E) return;
  int d = dst[e];
  unsigned long long add = (1ull << 40) |
      (unsigned long long)(eattr[e] * 16777216.0f);
  unsigned long long old = atomicAdd(&degp[d], add);
  rank[e] = (int)(old >> 40);
}

// ---------------------------------------------------------------- scan (3 phases)
__global__ __launch_bounds__(256) void k_scan1(const unsigned long long* __restrict__ degp,
    int* __restrict__ row_ptr, int* __restrict__ bsum, int n){
  __shared__ int sm[2][256];
  int tid = threadIdx.x, gid = blockIdx.x * 256 + tid;
  int v = (gid < n) ? (int)(degp[gid] >> 40) : 0;
  sm[0][tid] = v; __syncthreads();
  int pin = 0;
  for (int off = 1; off < 256; off <<= 1){
    int t = sm[pin][tid];
    if (tid >= off) t += sm[pin][tid - off];
    sm[pin ^ 1][tid] = t; pin ^= 1; __syncthreads();
  }
  int incl = sm[pin][tid];
  if (gid < n) row_ptr[gid] = incl - v;
  if (tid == 255) bsum[blockIdx.x] = incl;
}

__global__ __launch_bounds__(256) void k_scan2(const int* __restrict__ bsum,
    int* __restrict__ bofs, int nb){
  __shared__ int sm[2][256];
  int tid = threadIdx.x;
  int v = (tid < nb) ? bsum[tid] : 0;
  sm[0][tid] = v; __syncthreads();
  int pin = 0;
  for (int off = 1; off < 256; off <<= 1){
    int t = sm[pin][tid];
    if (tid >= off) t += sm[pin][tid - off];
    sm[pin ^ 1][tid] = t; pin ^= 1; __syncthreads();
  }
  bofs[tid] = sm[pin][tid] - v;
}

__global__ __launch_bounds__(256) void k_scan3(int* __restrict__ row_ptr,
    const int* __restrict__ bofs, const unsigned long long* __restrict__ degp,
    float* __restrict__ lattr, int n, int E){
  int gid = blockIdx.x * 256 + threadIdx.x;
  if (gid >= n) return;
  row_ptr[gid] += bofs[gid >> 8];
  unsigned long long p = degp[gid];
  float d = (float)(int)(p >> 40);
  float s = (float)(p & ((1ull << 40) - 1)) * (1.0f / 16777216.0f);
  lattr[gid] = s / fmaxf(d, 1.0f);
  if (gid == 0) row_ptr[n] = E;
}

// ---------------------------------------------------------------- CSR scatter (no atomics)
__global__ __launch_bounds__(256) void k_scatter(const int* __restrict__ src,
    const int* __restrict__ dst, const float* __restrict__ eattr,
    const int* __restrict__ row_ptr, const int* __restrict__ rank,
    int4* __restrict__ csr4, int E){
  int e = blockIdx.x * 256 + threadIdx.x;
  if (e >= E) return;
  int d = dst[e];
  int pos = row_ptr[d] + rank[e];
  csr4[pos] = make_int4(src[e], d, __float_as_int(eattr[e]), 0);
}

// ---------------------------------------------------------------- pack B into MFMA frag layout
__global__ void k_packB(const float* __restrict__ W, unsigned short* __restrict__ Bp,
                        int K, int N){
  int lane = threadIdx.x;
  int nt = blockIdx.x, kc = blockIdx.y, nkc = gridDim.y;
  int col = nt * 16 + (lane & 15);
  int krow = kc * 32 + (lane >> 4) * 8;
  unsigned short tmp[8];
#pragma unroll
  for (int j = 0; j < 8; j++) tmp[j] = f2bf(W[(size_t)(krow + j) * N + col]);
  unsigned short* dstp = Bp + (((size_t)nt * nkc + kc) * 64 + lane) * 8;
  *(ushort4*)(dstp)     = make_ushort4(tmp[0], tmp[1], tmp[2], tmp[3]);
  *(ushort4*)(dstp + 4) = make_ushort4(tmp[4], tmp[5], tmp[6], tmp[7]);
}

// ---------------------------------------------------------------- bf16 MFMA GEMM (bf16 A)
template<int N, int K>
__global__ __launch_bounds__(256) void k_gemm_mfma(const unsigned short* __restrict__ A,
    const unsigned short* __restrict__ Bp, unsigned short* __restrict__ C, int M){
  constexpr int NKC = K / 32, NNT = N / 16;
  __shared__ unsigned short Bs[N * K];
  {
    const uint4* srcp = (const uint4*)Bp;
    uint4* dstp = (uint4*)Bs;
    const int total = (N * K * 2) / 16;
    for (int i = threadIdx.x; i < total; i += 256) dstp[i] = srcp[i];
  }
  __syncthreads();
  int wave = threadIdx.x >> 6, lane = threadIdx.x & 63;
  int quad = lane >> 4, col = lane & 15;
  int r0 = (blockIdx.x * 4 + wave) * 16;
  int rowc = min(r0 + col, M - 1);
  short8 af[NKC];
#pragma unroll
  for (int kc = 0; kc < NKC; kc++)
    af[kc] = *(const short8*)(A + (size_t)rowc * K + kc * 32 + quad * 8);
  floatx4 acc[NNT];
#pragma unroll
  for (int nt = 0; nt < NNT; nt++) acc[nt] = (floatx4){0.f, 0.f, 0.f, 0.f};
#pragma unroll
  for (int kc = 0; kc < NKC; kc++){
#pragma unroll
    for (int nt = 0; nt < NNT; nt++){
      short8 bfv = *(const short8*)(&Bs[((nt * NKC + kc) * 64 + lane) * 8]);
      acc[nt] = __builtin_amdgcn_mfma_f32_16x16x32_bf16(af[kc], bfv, acc[nt], 0, 0, 0);
    }
  }
#pragma unroll
  for (int nt = 0; nt < NNT; nt++){
#pragma unroll
    for (int i = 0; i < 4; i++){
      int r = r0 + quad * 4 + i;
      if (r < M) C[(size_t)r * N + nt * 16 + col] = f2bf(acc[nt][i]);
    }
  }
}

// ---------------------------------------------------------------- bf16 MFMA GEMM, fp32 A (fused cast)
template<int N, int K>
__global__ __launch_bounds__(256) void k_gemm_mfma_f32(const float* __restrict__ A,
    const unsigned short* __restrict__ Bp, unsigned short* __restrict__ C, int M){
  constexpr int NKC = K / 32, NNT = N / 16;
  __shared__ unsigned short Bs[N * K];
  {
    const uint4* srcp = (const uint4*)Bp;
    uint4* dstp = (uint4*)Bs;
    const int total = (N * K * 2) / 16;
    for (int i = threadIdx.x; i < total; i += 256) dstp[i] = srcp[i];
  }
  __syncthreads();
  int wave = threadIdx.x >> 6, lane = threadIdx.x & 63;
  int quad = lane >> 4, col = lane & 15;
  int r0 = (blockIdx.x * 4 + wave) * 16;
  int rowc = min(r0 + col, M - 1);
  short8 af[NKC];
#pragma unroll
  for (int kc = 0; kc < NKC; kc++){
    float4 a0 = *(const float4*)(A + (size_t)rowc * K + kc * 32 + quad * 8);
    float4 a1 = *(const float4*)(A + (size_t)rowc * K + kc * 32 + quad * 8 + 4);
    short8 t;
    t[0] = (short)f2bf(a0.x); t[1] = (short)f2bf(a0.y);
    t[2] = (short)f2bf(a0.z); t[3] = (short)f2bf(a0.w);
    t[4] = (short)f2bf(a1.x); t[5] = (short)f2bf(a1.y);
    t[6] = (short)f2bf(a1.z); t[7] = (short)f2bf(a1.w);
    af[kc] = t;
  }
  floatx4 acc[NNT];
#pragma unroll
  for (int nt = 0; nt < NNT; nt++) acc[nt] = (floatx4){0.f, 0.f, 0.f, 0.f};
#pragma unroll
  for (int kc = 0; kc < NKC; kc++){
#pragma unroll
    for (int nt = 0; nt < NNT; nt++){
      short8 bfv = *(const short8*)(&Bs[((nt * NKC + kc) * 64 + lane) * 8]);
      acc[nt] = __builtin_amdgcn_mfma_f32_16x16x32_bf16(af[kc], bfv, acc[nt], 0, 0, 0);
    }
  }
#pragma unroll
  for (int nt = 0; nt < NNT; nt++){
#pragma unroll
    for (int i = 0; i < 4; i++){
      int r = r0 + quad * 4 + i;
      if (r < M) C[(size_t)r * N + nt * 16 + col] = f2bf(acc[nt][i]);
    }
  }
}

// ---------------------------------------------------------------- edge coeffs
__global__ void k_ce(const float* __restrict__ We1, const float* __restrict__ ae1,
    const float* __restrict__ We2, const float* __restrict__ ae2,
    float* __restrict__ ce){
  int lane = threadIdx.x;
  float p0 = We1[lane]       * ae1[lane];
  float p1 = We1[64 + lane]  * ae1[64 + lane];
  float p2 = We1[128 + lane] * ae1[128 + lane];
  float p3 = We1[192 + lane] * ae1[192 + lane];
  float p4 = We2[lane]       * ae2[lane];
  p0 = wsumf(p0); p1 = wsumf(p1); p2 = wsumf(p2); p3 = wsumf(p3); p4 = wsumf(p4);
  if (lane == 0){ ce[0] = p0; ce[1] = p1; ce[2] = p2; ce[3] = p3; ce[4] = p4; }
}

// ---------------------------------------------------------------- att scores L1 (bf16 h)
__global__ __launch_bounds__(256) void k_attscore1(const unsigned short* __restrict__ h,
    const float* __restrict__ as_, const float* __restrict__ ad_,
    float* __restrict__ a_src, float* __restrict__ a_dst, int n){
  int node = blockIdx.x * 4 + (threadIdx.x >> 6);
  if (node >= n) return;
  int lane = threadIdx.x & 63;
  ushort4 hv = *(const ushort4*)(h + (size_t)node * 256 + lane * 4);
  float4 av = *(const float4*)(as_ + lane * 4);
  float4 dv = *(const float4*)(ad_ + lane * 4);
  float h0 = bf2f(hv.x), h1 = bf2f(hv.y), h2 = bf2f(hv.z), h3 = bf2f(hv.w);
  float s = h0 * av.x + h1 * av.y + h2 * av.z + h3 * av.w;
  float d = h0 * dv.x + h1 * dv.y + h2 * dv.z + h3 * dv.w;
  s = wsumf16(s); d = wsumf16(d);
  if ((lane & 15) == 0){
    a_src[node * 4 + (lane >> 4)] = s;
    a_dst[node * 4 + (lane >> 4)] = d;
  }
}

// ---------------------------------------------------------------- edge weight prepass L1
__global__ __launch_bounds__(256) void k_wpre1(const int4* __restrict__ csr4,
    const float* __restrict__ a_src, const float* __restrict__ a_dst,
    const float* __restrict__ ce, int4* __restrict__ wcsr, int E){
  int e = blockIdx.x * 256 + threadIdx.x;
  if (e >= E) return;
  int4 c = csr4[e];
  float ea = __int_as_float(c.z);
  float4 as4 = *(const float4*)(a_src + (size_t)c.x * 4);
  float4 ad4 = *(const float4*)(a_dst + (size_t)c.y * 4);
  float4 ce4 = *(const float4*)ce;
  float a0 = as4.x + ad4.x + ea * ce4.x; a0 = a0 > 0.f ? a0 : 0.2f * a0;
  float a1 = as4.y + ad4.y + ea * ce4.y; a1 = a1 > 0.f ? a1 : 0.2f * a1;
  float a2 = as4.z + ad4.z + ea * ce4.z; a2 = a2 > 0.f ? a2 : 0.2f * a2;
  float a3 = as4.w + ad4.w + ea * ce4.w; a3 = a3 > 0.f ? a3 : 0.2f * a3;
  unsigned u01 = pack_h2(__expf(a0), __expf(a1));
  unsigned u23 = pack_h2(__expf(a2), __expf(a3));
  wcsr[e] = make_int4(c.x, (int)u01, (int)u23, 0);
}

// ---------------------------------------------------------------- GAT layer 1
// Quarter-wave (16 lanes) per edge, 4 edges/iter; lane covers 16 channels (32 B).
__global__ __launch_bounds__(256) void k_gat1(
    const int* __restrict__ row_ptr, const int4* __restrict__ wcsr,
    const float* __restrict__ lattr,
    const float* __restrict__ a_src, const float* __restrict__ a_dst,
    const float* __restrict__ ce, const unsigned short* __restrict__ hpre,
    const float* __restrict__ bias, unsigned short* __restrict__ hout, int n){
  int node = blockIdx.x * 4 + (threadIdx.x >> 6);
  if (node >= n) return;
  int lane = threadIdx.x & 63;
  int q = lane >> 4, lsub = lane & 15, hq = lsub >> 2;
  int start = row_ptr[node], deg = row_ptr[node + 1] - start;
  int total = deg + 1;
  float4 as4 = *(const float4*)(a_src + (size_t)node * 4);
  float4 ad4 = *(const float4*)(a_dst + (size_t)node * 4);
  float4 ce4 = *(const float4*)ce;
  float la = lattr[node];
  float asvh = hq == 0 ? as4.x : hq == 1 ? as4.y : hq == 2 ? as4.z : as4.w;
  float advh = hq == 0 ? ad4.x : hq == 1 ? ad4.y : hq == 2 ? ad4.z : ad4.w;
  float ceh  = hq == 0 ? ce4.x : hq == 1 ? ce4.y : hq == 2 ? ce4.z : ce4.w;
  float aself = asvh + advh + la * ceh;
  aself = aself > 0.f ? aself : 0.2f * aself;
  float wself = __expf(aself);
  float acc[16];
#pragma unroll
  for (int k = 0; k < 16; k++) acc[k] = 0.f;
  float dn = 0.f;
  for (int e = q; e < total; e += 4){
    int s; float wv;
    if (e < deg){
      int4 we = wcsr[start + e];
      s = we.x;
      unsigned wb = (hq & 2) ? (unsigned)we.z : (unsigned)we.y;
      wv = unpack_h(wb, hq & 1);
    } else { s = node; wv = wself; }
    dn += wv;
    const unsigned short* hp = hpre + (size_t)s * 256 + lsub * 16;
    ushort8_t hv0 = *(const ushort8_t*)(hp);
    ushort8_t hv1 = *(const ushort8_t*)(hp + 8);
#pragma unroll
    for (int k = 0; k < 8; k++) acc[k]     += wv * bf2f(hv0[k]);
#pragma unroll
    for (int k = 0; k < 8; k++) acc[k + 8] += wv * bf2f(hv1[k]);
  }
  dn += __shfl_xor(dn, 16, 64);
  dn += __shfl_xor(dn, 32, 64);
#pragma unroll
  for (int k = 0; k < 16; k++){
    acc[k] += __shfl_xor(acc[k], 16, 64);
    acc[k] += __shfl_xor(acc[k], 32, 64);
  }
  if (q == 0){
    float inv = 1.f / dn;
    float bb[16];
#pragma unroll
    for (int j = 0; j < 4; j++){
      float4 b4 = *(const float4*)(bias + lsub * 16 + j * 4);
      bb[j * 4 + 0] = b4.x; bb[j * 4 + 1] = b4.y;
      bb[j * 4 + 2] = b4.z; bb[j * 4 + 3] = b4.w;
    }
    ushort8_t o0, o1;
#pragma unroll
    for (int k = 0; k < 8; k++){
      float v = acc[k] * inv + bb[k];
      v = v > 0.f ? v : (__expf(v) - 1.f);
      o0[k] = f2bf(v);
    }
#pragma unroll
    for (int k = 0; k < 8; k++){
      float v = acc[k + 8] * inv + bb[k + 8];
      v = v > 0.f ? v : (__expf(v) - 1.f);
      o1[k] = f2bf(v);
    }
    unsigned short* op = hout + (size_t)node * 256 + lsub * 16;
    *(ushort8_t*)(op)     = o0;
    *(ushort8_t*)(op + 8) = o1;
  }
}

// ---------------------------------------------------------------- att scores L2 (bf16 h)
__global__ __launch_bounds__(256) void k_attscore2(const unsigned short* __restrict__ h,
    const float* __restrict__ as_, const float* __restrict__ ad_,
    float* __restrict__ a_src, float* __restrict__ a_dst, int n){
  int node = blockIdx.x * 4 + (threadIdx.x >> 6);
  if (node >= n) return;
  int lane = threadIdx.x & 63;
  float v = bf2f(h[(size_t)node * 64 + lane]);
  float s = wsumf(v * as_[lane]);
  float d = wsumf(v * ad_[lane]);
  if (lane == 0){ a_src[node] = s; a_dst[node] = d; }
}

// ---------------------------------------------------------------- edge weight prepass L2
__global__ __launch_bounds__(256) void k_wpre2(const int4* __restrict__ csr4,
    const float* __restrict__ a_src, const float* __restrict__ a_dst,
    const float* __restrict__ ce, int2* __restrict__ wcsr2, int E){
  int e = blockIdx.x * 256 + threadIdx.x;
  if (e >= E) return;
  int4 c = csr4[e];
  float ea = __int_as_float(c.z);
  float a = a_src[c.x] + a_dst[c.y] + ea * ce[4];
  a = a > 0.f ? a : 0.2f * a;
  wcsr2[e] = make_int2(c.x, __float_as_int(__expf(a)));
}

// ---------------------------------------------------------------- GAT layer 2 + pair projection
__global__ __launch_bounds__(256) void k_gat2(
    const int* __restrict__ row_ptr, const int2* __restrict__ wcsr2,
    const float* __restrict__ lattr,
    const float* __restrict__ a_src, const float* __restrict__ a_dst,
    const float* __restrict__ ce, const unsigned short* __restrict__ hpre,
    const float* __restrict__ bias, const float* __restrict__ Wlin,
    float* __restrict__ s1v, float* __restrict__ s2v, int n){
  int node = blockIdx.x * 4 + (threadIdx.x >> 6);
  if (node >= n) return;
  int lane = threadIdx.x & 63;
  int slot = lane >> 3, lsub = lane & 7;
  int start = row_ptr[node], deg = row_ptr[node + 1] - start;
  int total = deg + 1;
  float aself = a_src[node] + a_dst[node] + lattr[node] * ce[4];
  aself = aself > 0.f ? aself : 0.2f * aself;
  float wself = __expf(aself);
  float acc[8] = {0.f,0.f,0.f,0.f,0.f,0.f,0.f,0.f};
  float dn = 0.f;
  for (int e = slot; e < total; e += 8){
    int s; float wv;
    if (e < deg){ int2 se = wcsr2[start + e]; s = se.x; wv = __int_as_float(se.y); }
    else        { s = node; wv = wself; }
    dn += wv;
    ushort8_t hv = *(const ushort8_t*)(hpre + (size_t)s * 64 + lsub * 8);
#pragma unroll
    for (int k = 0; k < 8; k++) acc[k] += wv * bf2f(hv[k]);
  }
#pragma unroll
  for (int o = 8; o < 64; o <<= 1){
    dn += __shfl_xor(dn, o, 64);
#pragma unroll
    for (int k = 0; k < 8; k++) acc[k] += __shfl_xor(acc[k], o, 64);
  }
  float inv = 1.f / dn;
  float t1 = 0.f, t2 = 0.f;
#pragma unroll
  for (int k = 0; k < 8; k++){
    float v = acc[k] * inv + bias[lsub * 8 + k];
    t1 += v * Wlin[lsub * 8 + k];
    t2 += v * Wlin[64 + lsub * 8 + k];
  }
#pragma unroll
  for (int o = 1; o < 8; o <<= 1){
    t1 += __shfl_xor(t1, o, 64);
    t2 += __shfl_xor(t2, o, 64);
  }
  if (lane == 0){ s1v[node] = t1; s2v[node] = t2; }
}

// ---------------------------------------------------------------- pair head
__global__ __launch_bounds__(256) void k_pairs(const int* __restrict__ pairs,
    const float* __restrict__ s1v, const float* __restrict__ s2v,
    const float* __restrict__ blin, float* __restrict__ out, int P){
  int p = blockIdx.x * 256 + threadIdx.x;
  if (p >= P) return;
  int i = pairs[2 * p], j = pairs[2 * p + 1];
  float x = s1v[i] + s2v[j] + blin[0];
  out[p] = 1.f / (1.f + __expf(-x));
}

// ---------------------------------------------------------------- launch
extern "C" void kernel_launch(void* const* d_in, const int* in_sizes, int n_in,
                              void* d_out, int out_size, void* d_ws, size_t ws_size,
                              hipStream_t stream) {
  const float* x     = (const float*)d_in[0];
  const int*   esrc  = (const int*)  d_in[1];
  const int*   edst  = (const int*)  d_in[2];
  const float* eattr = (const float*)d_in[3];
  const int*   pairs = (const int*)  d_in[4];
  const float* W1    = (const float*)d_in[5];
  const float* We1   = (const float*)d_in[6];
  const float* as1   = (const float*)d_in[7];
  const float* ad1   = (const float*)d_in[8];
  const float* ae1   = (const float*)d_in[9];
  const float* b1    = (const float*)d_in[10];
  const float* W2    = (const float*)d_in[11];
  const float* We2   = (const float*)d_in[12];
  const float* as2   = (const float*)d_in[13];
  const float* ad2   = (const float*)d_in[14];
  const float* ae2   = (const float*)d_in[15];
  const float* b2    = (const float*)d_in[16];
  const float* Wlin  = (const float*)d_in[17];
  const float* blin  = (const float*)d_in[18];
  float* out = (float*)d_out;

  const int N = in_sizes[0] / 128;
  const int E = in_sizes[1];
  const int P = in_sizes[4] / 2;

  char* w = (char*)d_ws;
  size_t off = 0;
  auto alloc = [&](size_t bytes) -> size_t {
    size_t r = off; off = (off + bytes + 255) & ~(size_t)255; return r;
  };
  size_t o_degp   = alloc((size_t)N * 8);
  size_t zero_end = off;
  size_t o_rank   = alloc((size_t)E * 4);
  size_t o_rowptr = alloc((size_t)(N + 1) * 4);
  size_t o_bsum   = alloc(1024);
  size_t o_bofs   = alloc(1024);
  size_t o_lattr  = alloc((size_t)N * 4);
  size_t o_csr4   = alloc((size_t)E * 16);
  size_t o_wcsr1  = alloc((size_t)E * 16);
  size_t o_wcsr2  = alloc((size_t)E * 8);
  size_t o_asrc1  = alloc((size_t)N * 16);
  size_t o_adst1  = alloc((size_t)N * 16);
  size_t o_asrc2  = alloc((size_t)N * 4);
  size_t o_adst2  = alloc((size_t)N * 4);
  size_t o_ce     = alloc(32);
  size_t o_s1     = alloc((size_t)N * 4);
  size_t o_s2     = alloc((size_t)N * 4);
  size_t o_W1p    = alloc(128 * 256 * 2);
  size_t o_W2p    = alloc(256 * 64 * 2);
  size_t o_h1preb = alloc((size_t)N * 256 * 2);
  size_t o_h1b    = alloc((size_t)N * 256 * 2);
  size_t o_h2preb = alloc((size_t)N * 64 * 2);
  (void)ws_size;

  unsigned long long* degp = (unsigned long long*)(w + o_degp);
  int*   rank   = (int*)  (w + o_rank);
  int*   rowptr = (int*)  (w + o_rowptr);
  int*   bsum   = (int*)  (w + o_bsum);
  int*   bofs   = (int*)  (w + o_bofs);
  float* lattr  = (float*)(w + o_lattr);
  int4*  csr4   = (int4*) (w + o_csr4);
  int4*  wcsr1  = (int4*) (w + o_wcsr1);
  int2*  wcsr2  = (int2*) (w + o_wcsr2);
  float* asrc1  = (float*)(w + o_asrc1);
  float* adst1  = (float*)(w + o_adst1);
  float* asrc2  = (float*)(w + o_asrc2);
  float* adst2  = (float*)(w + o_adst2);
  float* ce     = (float*)(w + o_ce);
  float* s1v    = (float*)(w + o_s1);
  float* s2v    = (float*)(w + o_s2);
  unsigned short* W1p    = (unsigned short*)(w + o_W1p);
  unsigned short* W2p    = (unsigned short*)(w + o_W2p);
  unsigned short* h1preb = (unsigned short*)(w + o_h1preb);
  unsigned short* h1b    = (unsigned short*)(w + o_h1b);
  unsigned short* h2preb = (unsigned short*)(w + o_h2preb);

  hipMemsetAsync(w, 0, zero_end, stream);

  int ebl = (E + 255) / 256;
  int nbl = (N + 255) / 256;
  int wbl = (N + 3) / 4;

  // CSR build (single packed-u64 atomic round; scatter atomic-free)
  k_count<<<ebl, 256, 0, stream>>>(edst, eattr, degp, rank, E);
  k_scan1<<<nbl, 256, 0, stream>>>(degp, rowptr, bsum, N);
  k_scan2<<<1, 256, 0, stream>>>(bsum, bofs, nbl);
  k_scan3<<<nbl, 256, 0, stream>>>(rowptr, bofs, degp, lattr, N, E);
  k_scatter<<<ebl, 256, 0, stream>>>(esrc, edst, eattr, rowptr, rank, csr4, E);

  // weight packing + edge coeffs
  k_packB<<<dim3(16, 4), 64, 0, stream>>>(W1, W1p, 128, 256);
  k_packB<<<dim3(4, 8), 64, 0, stream>>>(W2, W2p, 256, 64);
  k_ce<<<1, 64, 0, stream>>>(We1, ae1, We2, ae2, ce);

  // layer 1
  k_gemm_mfma_f32<256, 128><<<(N + 63) / 64, 256, 0, stream>>>(x, W1p, h1preb, N);
  k_attscore1<<<wbl, 256, 0, stream>>>(h1preb, as1, ad1, asrc1, adst1, N);
  k_wpre1<<<ebl, 256, 0, stream>>>(csr4, asrc1, adst1, ce, wcsr1, E);
  k_gat1<<<wbl, 256, 0, stream>>>(rowptr, wcsr1, lattr, asrc1, adst1, ce,
                                  h1preb, b1, h1b, N);
  // layer 2
  k_gemm_mfma<64, 256><<<(N + 63) / 64, 256, 0, stream>>>(h1b, W2p, h2preb, N);
  k_attscore2<<<wbl, 256, 0, stream>>>(h2preb, as2, ad2, asrc2, adst2, N);
  k_wpre2<<<ebl, 256, 0, stream>>>(csr4, asrc2, adst2, ce, wcsr2, E);
  k_gat2<<<wbl, 256, 0, stream>>>(rowptr, wcsr2, lattr, asrc2, adst2, ce,
                                  h2preb, b2, Wlin, s1v, s2v, N);
  // pair head
  k_pairs<<<(P + 255) / 256, 256, 0, stream>>>(pairs, s1v, s2v, blin, out, P);
}